// Round 1
// baseline (190.089 us; speedup 1.0000x reference)
//
#include <hip/hip_runtime.h>
#include <hip/hip_bf16.h>
#include <math.h>

#define N_Q   512
#define M_ALL 2048
#define CHN   256
#define TOPK  6
#define BLOCK 256
#define MPT   (M_ALL / BLOCK)   // 8 m-rows per thread

__global__ __launch_bounds__(BLOCK) void gcn_main(
    const float* __restrict__ micro,      // [N,C]
    const float* __restrict__ label,      // [N]
    const float* __restrict__ micro_all,  // [M,C]
    const float* __restrict__ label_all,  // [M]
    const float* __restrict__ fc_w,       // [C]
    float* __restrict__ out,              // [N*C + 1]
    float* __restrict__ loss_accum)       // [1], pre-zeroed
{
    __shared__ float s_micro[CHN];
    __shared__ float s_w[CHN];
    __shared__ float s_red[BLOCK];
    __shared__ int   s_redi[BLOCK];

    const int n = blockIdx.x;
    const int t = threadIdx.x;

    // Stage query row + effective weight (fc_w - 1/C) in LDS
    s_micro[t] = micro[n * CHN + t];
    s_w[t]     = fc_w[t] - (1.0f / (float)CHN);
    __syncthreads();

    // ---- Phase 1: logits.  anti[n,m] = sum_c (a-b)^2 * w[c] ----
    float logit[MPT];
    for (int j = 0; j < MPT; ++j) {
        const int m = t + j * BLOCK;
        const float4* row = (const float4*)(micro_all + (size_t)m * CHN);
        float acc = 0.0f;
        #pragma unroll 8
        for (int c4 = 0; c4 < CHN / 4; ++c4) {
            float4 a = row[c4];
            const int c = c4 * 4;
            float d0 = a.x - s_micro[c + 0];
            float d1 = a.y - s_micro[c + 1];
            float d2 = a.z - s_micro[c + 2];
            float d3 = a.w - s_micro[c + 3];
            acc += d0 * d0 * s_w[c + 0];
            acc += d1 * d1 * s_w[c + 1];
            acc += d2 * d2 * s_w[c + 2];
            acc += d3 * d3 * s_w[c + 3];
        }
        logit[j] = acc;
    }

    // ---- Phase 2: top-6 via repeated block argmax ----
    int   top_idx[TOPK];
    float top_val[TOPK];
    unsigned taken = 0u;   // per-thread exclusion mask over its MPT slots

    for (int k = 0; k < TOPK; ++k) {
        float best  = -INFINITY;
        int   bestj = -1;
        #pragma unroll
        for (int j = 0; j < MPT; ++j) {
            bool avail = ((taken >> j) & 1u) == 0u;
            if (avail && logit[j] > best) { best = logit[j]; bestj = j; }
        }
        s_red[t]  = best;
        s_redi[t] = (bestj < 0) ? -1 : (t + bestj * BLOCK);
        __syncthreads();
        for (int s = BLOCK / 2; s > 0; s >>= 1) {
            if (t < s) {
                if (s_red[t + s] > s_red[t]) {
                    s_red[t]  = s_red[t + s];
                    s_redi[t] = s_redi[t + s];
                }
            }
            __syncthreads();
        }
        const int   gi = s_redi[0];
        const float gv = s_red[0];
        __syncthreads();   // protect s_red reuse next iteration

        top_idx[k] = gi;
        top_val[k] = gv;
        // owner thread of gi marks its slot taken:  m = t + j*BLOCK
        if ((gi & (BLOCK - 1)) == t) taken |= 1u << (gi >> 8);
    }

    // ---- Phase 3: softmax over the 6 selected logits ----
    const float mx = top_val[0];     // first argmax is the global max
    float e[TOPK];
    float esum = 0.0f;
    #pragma unroll
    for (int k = 0; k < TOPK; ++k) { e[k] = __expf(top_val[k] - mx); esum += e[k]; }
    const float inv = 1.0f / esum;

    // ---- Phase 4: epilogue.  micro_tmp[n,c] = micro[n,c] + sum_k cut_k * micro_all[idx_k, c]
    float outv = s_micro[t];
    #pragma unroll
    for (int k = 0; k < TOPK; ++k) {
        outv += (e[k] * inv) * micro_all[(size_t)top_idx[k] * CHN + t];
    }
    out[n * CHN + t] = outv;

    if (t == 0) {
        const float lab = label[n];
        float l = 0.0f;
        #pragma unroll
        for (int k = 0; k < TOPK; ++k) {
            l += (e[k] * inv) * fabsf(label_all[top_idx[k]] - lab);
        }
        atomicAdd(loss_accum, l);
    }
}

__global__ void gcn_finalize(const float* __restrict__ loss_accum,
                             float* __restrict__ out)
{
    out[N_Q * CHN] = 1e-4f + loss_accum[0] / (float)N_Q;
}

extern "C" void kernel_launch(void* const* d_in, const int* in_sizes, int n_in,
                              void* d_out, int out_size, void* d_ws, size_t ws_size,
                              hipStream_t stream) {
    const float* micro     = (const float*)d_in[0];
    const float* label     = (const float*)d_in[1];
    const float* micro_all = (const float*)d_in[2];
    const float* label_all = (const float*)d_in[3];
    const float* fc_w      = (const float*)d_in[4];
    float* out        = (float*)d_out;
    float* loss_accum = (float*)d_ws;

    hipMemsetAsync(loss_accum, 0, sizeof(float), stream);
    gcn_main<<<N_Q, BLOCK, 0, stream>>>(micro, label, micro_all, label_all,
                                        fc_w, out, loss_accum);
    gcn_finalize<<<1, 1, 0, stream>>>(loss_accum, out);
}